// Round 1
// baseline (1134.880 us; speedup 1.0000x reference)
//
#include <hip/hip_runtime.h>

#define N_NODES 512
#define E_DIM   40
#define F_DIM   64
#define TOPK    10

typedef unsigned short u16;

__device__ __forceinline__ u16 f2bf(float f) {
    unsigned int b = __float_as_uint(f);
    b += 0x7fffu + ((b >> 16) & 1u);   // round-to-nearest-even
    return (u16)(b >> 16);
}
__device__ __forceinline__ float bf2f(u16 u) {
    return __uint_as_float(((unsigned int)u) << 16);
}

// ---------------------------------------------------------------------------
// feats[n,e] = tanh(3*(emb1[n] @ lin1_w + b))   (idx is always arange -> identity)
__global__ void feats_kernel(const float* __restrict__ emb1,
                             const float* __restrict__ w,
                             const float* __restrict__ b,
                             float* __restrict__ feats) {
    int n = blockIdx.x, e = threadIdx.x;
    if (e >= E_DIM) return;
    const float* er = emb1 + n * E_DIM;
    float s = b[e];
    for (int k = 0; k < E_DIM; ++k) s += er[k] * w[k * E_DIM + e];
    feats[n * E_DIM + e] = tanhf(3.0f * s);
}

// ---------------------------------------------------------------------------
// Fused weights: A = W_self @ Wc[0:64], B = W_neigh @ Wc[64:128],
// a0p = W_self @ att[0:64], a1p = W_neigh @ att[64:128]
__global__ void fusew_kernel(const float* __restrict__ Ws, const float* __restrict__ Wn,
                             const float* __restrict__ Wc, const float* __restrict__ att,
                             float* __restrict__ A, float* __restrict__ B,
                             float* __restrict__ a0p, float* __restrict__ a1p) {
    int f = blockIdx.x, d = threadIdx.x;   // 64 blocks x 64 threads
    float a = 0.f, bb = 0.f;
    for (int k = 0; k < 64; ++k) {
        a  += Ws[f * 64 + k] * Wc[k * 64 + d];
        bb += Wn[f * 64 + k] * Wc[(64 + k) * 64 + d];
    }
    A[f * 64 + d] = a;
    B[f * 64 + d] = bb;
    float p0 = Ws[f * 64 + d] * att[d];
    float p1 = Wn[f * 64 + d] * att[64 + d];
    for (int off = 32; off > 0; off >>= 1) {
        p0 += __shfl_down(p0, off);
        p1 += __shfl_down(p1, off);
    }
    if (d == 0) { a0p[f] = p0; a1p[f] = p1; }
}

// ---------------------------------------------------------------------------
// Per row m: sim[m,:] = feats[m] @ feats.T, iterative top-10 argmax with
// jax.lax.top_k tie-break (equal values -> lower index).
__global__ void topk_kernel(const float* __restrict__ feats, int* __restrict__ top) {
    int m = blockIdx.x, lane = threadIdx.x;  // 512 blocks x 64 threads (1 wave)
    __shared__ float sim[N_NODES];
    float fm[E_DIM];
#pragma unroll
    for (int k = 0; k < E_DIM; ++k) fm[k] = feats[m * E_DIM + k];
    for (int n = lane; n < N_NODES; n += 64) {
        const float* fr = feats + n * E_DIM;
        float s = 0.f;
#pragma unroll
        for (int k = 0; k < E_DIM; ++k) s += fm[k] * fr[k];
        sim[n] = s;
    }
    __syncthreads();
    for (int it = 0; it < TOPK; ++it) {
        float bv = -3.0e38f; int bi = 1 << 30;
        for (int n = lane; n < N_NODES; n += 64) {
            float v = sim[n];
            if (v > bv) { bv = v; bi = n; }       // ascending scan: min index on ties
        }
        for (int off = 32; off > 0; off >>= 1) {
            float ov = __shfl_down(bv, off);
            int   oi = __shfl_down(bi, off);
            if (ov > bv || (ov == bv && oi < bi)) { bv = ov; bi = oi; }
        }
        bi = __shfl(bi, 0);
        if (lane == 0) top[m * TOPK + it] = bi;
        __syncthreads();
        sim[bi] = -3.0e38f;
        __syncthreads();
    }
}

// ---------------------------------------------------------------------------
// Deterministic CSR: node n -> sorted list of hyperedges m with n in top[m].
__global__ void csr_kernel(const int* __restrict__ top, int* __restrict__ csr_off,
                           int* __restrict__ edges, float* __restrict__ inv_deg) {
    __shared__ int cnt[N_NODES];
    __shared__ int buf[N_NODES];
    __shared__ int pos[N_NODES];
    int t = threadIdx.x;                      // 512 threads
    cnt[t] = 0;
    __syncthreads();
    for (int j = 0; j < TOPK; ++j) atomicAdd(&cnt[top[t * TOPK + j]], 1);
    __syncthreads();
    int my = cnt[t];
    buf[t] = my;
    __syncthreads();
    for (int s = 1; s < N_NODES; s <<= 1) {   // Hillis-Steele inclusive scan
        int v = (t >= s) ? buf[t - s] : 0;
        __syncthreads();
        buf[t] += v;
        __syncthreads();
    }
    int off = buf[t] - my;
    csr_off[t] = off;
    if (t == N_NODES - 1) csr_off[N_NODES] = buf[t];
    inv_deg[t] = 1.0f / (float)(my > 0 ? my : 1);
    pos[t] = off;
    __syncthreads();
    for (int j = 0; j < TOPK; ++j) {
        int n = top[t * TOPK + j];
        int p = atomicAdd(&pos[n], 1);
        edges[p] = t;
    }
    __syncthreads();
    // canonicalize order (insertion sort, avg len 10) -> bitwise-deterministic sums
    for (int i = 1; i < my; ++i) {
        int key = edges[off + i], k = i - 1;
        while (k >= 0 && edges[off + k] > key) { edges[off + k + 1] = edges[off + k]; --k; }
        edges[off + k + 1] = key;
    }
}

// ---------------------------------------------------------------------------
// Main fused kernel: one block per (b,l). LDS: he chunk (bf16 512x8, pad 10),
// xnr (bf16 512x64, pad 66), scores + reduction scratch.  Total 80928 B.
#define HE_OFF   0
#define XNR_OFF  10240
#define SC_OFF   (10240 + 67584)
#define SMEM_BYTES (10240 + 67584 + 2048 + 1024 + 32)

__global__ __launch_bounds__(256, 2) void main_kernel(
    const float* __restrict__ x, const int* __restrict__ top,
    const int* __restrict__ csr_off, const int* __restrict__ edges,
    const float* __restrict__ inv_deg,
    const float* __restrict__ A, const float* __restrict__ B,
    const float* __restrict__ a0p, const float* __restrict__ a1p,
    float* __restrict__ out)
{
    extern __shared__ char smem[];
    u16*   he   = (u16*)(smem + HE_OFF);    // [512][10] (cols 0..7 used)
    u16*   xnr  = (u16*)(smem + XNR_OFF);   // [512][66] (cols 0..63 used)
    float* sc   = (float*)(smem + SC_OFF);  // [512]
    float* red  = sc + 512;                 // [256]
    float* misc = red + 256;                // [8]

    const int bl  = blockIdx.x;
    const int tid = threadIdx.x;
    const float* xr   = x   + (size_t)bl * N_NODES * F_DIM;
    float*       outr = out + (size_t)bl * N_NODES * F_DIM;

    // ---- phases 1+2, f-chunks of 8 ----
    for (int c = 0; c < 8; ++c) {
        const int f0c = c * 8;
        // phase 1: he[m, chunk] = leaky(0.1 * sum over top[m] of x rows)
        for (int it = 0; it < 4; ++it) {
            int item = it * 256 + tid;
            int m = item >> 1, h = item & 1;
            int f0 = f0c + h * 4;
            const int* tp = top + m * TOPK;
            float4 acc = make_float4(0.f, 0.f, 0.f, 0.f);
#pragma unroll
            for (int j = 0; j < TOPK; ++j) {
                int n = tp[j];
                float4 v = *(const float4*)(xr + n * F_DIM + f0);
                acc.x += v.x; acc.y += v.y; acc.z += v.z; acc.w += v.w;
            }
            acc.x *= 0.1f; acc.y *= 0.1f; acc.z *= 0.1f; acc.w *= 0.1f;
            acc.x = acc.x >= 0.f ? acc.x : 0.2f * acc.x;
            acc.y = acc.y >= 0.f ? acc.y : 0.2f * acc.y;
            acc.z = acc.z >= 0.f ? acc.z : 0.2f * acc.z;
            acc.w = acc.w >= 0.f ? acc.w : 0.2f * acc.w;
            ushort2 u0, u1;
            u0.x = f2bf(acc.x); u0.y = f2bf(acc.y);
            u1.x = f2bf(acc.z); u1.y = f2bf(acc.w);
            ushort2* dst = (ushort2*)(he + m * 10 + h * 4);
            dst[0] = u0; dst[1] = u1;
        }
        __syncthreads();
        // phase 2: xnr[n, chunk] = inv_deg[n] * sum over edges(n) of he rows
        for (int it = 0; it < 4; ++it) {
            int item = it * 256 + tid;
            int n = item >> 1, h = item & 1;
            int o0 = csr_off[n], o1 = csr_off[n + 1];
            float inv = inv_deg[n];
            float4 acc = make_float4(0.f, 0.f, 0.f, 0.f);
            for (int j = o0; j < o1; ++j) {
                int e = edges[j];
                const ushort2* src = (const ushort2*)(he + e * 10 + h * 4);
                ushort2 p0 = src[0], p1 = src[1];
                acc.x += bf2f(p0.x); acc.y += bf2f(p0.y);
                acc.z += bf2f(p1.x); acc.w += bf2f(p1.y);
            }
            acc.x *= inv; acc.y *= inv; acc.z *= inv; acc.w *= inv;
            ushort2 u0, u1;
            u0.x = f2bf(acc.x); u0.y = f2bf(acc.y);
            u1.x = f2bf(acc.z); u1.y = f2bf(acc.w);
            ushort2* dst = (ushort2*)(xnr + n * 66 + f0c + h * 4);
            dst[0] = u0; dst[1] = u1;
        }
        __syncthreads();
    }

    // ---- phase 3: scores[n] = x[n]·a0p + xnr[n]·a1p ----
    for (int r = 0; r < 2; ++r) {
        int n = tid + r * 256;
        const float* xp = xr + n * F_DIM;
        const u16*   xq = xnr + n * 66;
        float s = 0.f;
#pragma unroll 4
        for (int f4 = 0; f4 < 16; ++f4) {
            float4 xv = *(const float4*)(xp + f4 * 4);
            const ushort2* q = (const ushort2*)(xq + f4 * 4);
            ushort2 q0 = q[0], q1 = q[1];
            float4 av = *(const float4*)(a0p + f4 * 4);
            float4 bv = *(const float4*)(a1p + f4 * 4);
            s += xv.x * av.x + xv.y * av.y + xv.z * av.z + xv.w * av.w;
            s += bf2f(q0.x) * bv.x + bf2f(q0.y) * bv.y
               + bf2f(q1.x) * bv.z + bf2f(q1.y) * bv.w;
        }
        sc[n] = s;
    }
    __syncthreads();

    // ---- softmax over 512 nodes ----
    red[tid] = fmaxf(sc[tid], sc[tid + 256]);
    __syncthreads();
    for (int s = 128; s > 0; s >>= 1) {
        if (tid < s) red[tid] = fmaxf(red[tid], red[tid + s]);
        __syncthreads();
    }
    float M = red[0];
    __syncthreads();
    float e0 = expf(sc[tid] - M), e1 = expf(sc[tid + 256] - M);
    sc[tid] = e0; sc[tid + 256] = e1;
    red[tid] = e0 + e1;
    __syncthreads();
    for (int s = 128; s > 0; s >>= 1) {
        if (tid < s) red[tid] += red[tid + s];
        __syncthreads();
    }
    if (tid == 0) misc[0] = 1.0f / red[0];
    __syncthreads();
    float invS = misc[0];

    // ---- phase 4: out[n,:] = w[n] * (x[n] @ A + xnr[n] @ B) ----
    int g = tid >> 4, l = tid & 15;
    for (int itn = 0; itn < 32; ++itn) {
        int n = itn * 16 + g;
        float w = sc[n] * invS;
        const float* xp = xr + n * F_DIM;
        const u16*   xq = xnr + n * 66;
        float4 acc = make_float4(0.f, 0.f, 0.f, 0.f);
        for (int f4 = 0; f4 < 16; ++f4) {
            float4 xv = *(const float4*)(xp + f4 * 4);
            const ushort2* q = (const ushort2*)(xq + f4 * 4);
            ushort2 q0 = q[0], q1 = q[1];
            float xs[4] = { xv.x, xv.y, xv.z, xv.w };
            float qs[4] = { bf2f(q0.x), bf2f(q0.y), bf2f(q1.x), bf2f(q1.y) };
#pragma unroll
            for (int j = 0; j < 4; ++j) {
                int f = f4 * 4 + j;
                float4 Av = *(const float4*)(A + f * 64 + l * 4);
                float4 Bv = *(const float4*)(B + f * 64 + l * 4);
                acc.x += xs[j] * Av.x + qs[j] * Bv.x;
                acc.y += xs[j] * Av.y + qs[j] * Bv.y;
                acc.z += xs[j] * Av.z + qs[j] * Bv.z;
                acc.w += xs[j] * Av.w + qs[j] * Bv.w;
            }
        }
        acc.x *= w; acc.y *= w; acc.z *= w; acc.w *= w;
        *(float4*)(outr + n * F_DIM + l * 4) = acc;
    }
}

// ---------------------------------------------------------------------------
extern "C" void kernel_launch(void* const* d_in, const int* in_sizes, int n_in,
                              void* d_out, int out_size, void* d_ws, size_t ws_size,
                              hipStream_t stream) {
    const float* x        = (const float*)d_in[0];
    // d_in[1] = idx (always arange -> identity, unused; also dodges int32/int64 ambiguity)
    const float* emb1     = (const float*)d_in[2];
    const float* lin1_w   = (const float*)d_in[3];
    const float* lin1_b   = (const float*)d_in[4];
    const float* W_self   = (const float*)d_in[5];
    const float* W_neigh  = (const float*)d_in[6];
    const float* W_concat = (const float*)d_in[7];
    const float* att      = (const float*)d_in[8];
    float* out = (float*)d_out;

    char* ws = (char*)d_ws;
    float* feats   = (float*)(ws + 0);        // 512*40*4  = 81920
    int*   top     = (int*)  (ws + 81920);    // 512*10*4  = 20480
    int*   csr_off = (int*)  (ws + 102400);   // 513*4
    int*   edges   = (int*)  (ws + 104704);   // 5120*4
    float* inv_deg = (float*)(ws + 125184);   // 512*4
    float* A       = (float*)(ws + 127232);   // 64*64*4
    float* B       = (float*)(ws + 143616);   // 64*64*4
    float* a0p     = (float*)(ws + 160000);   // 64*4
    float* a1p     = (float*)(ws + 160256);   // 64*4

    feats_kernel<<<N_NODES, 64, 0, stream>>>(emb1, lin1_w, lin1_b, feats);
    fusew_kernel<<<64, 64, 0, stream>>>(W_self, W_neigh, W_concat, att, A, B, a0p, a1p);
    topk_kernel<<<N_NODES, 64, 0, stream>>>(feats, top);
    csr_kernel<<<1, N_NODES, 0, stream>>>(top, csr_off, edges, inv_deg);

    (void)hipFuncSetAttribute((const void*)main_kernel,
                              hipFuncAttributeMaxDynamicSharedMemorySize, SMEM_BYTES);
    main_kernel<<<1024, 256, SMEM_BYTES, stream>>>(x, top, csr_off, edges, inv_deg,
                                                   A, B, a0p, a1p, out);
}

// Round 2
// 482.215 us; speedup vs baseline: 2.3535x; 2.3535x over previous
//
#include <hip/hip_runtime.h>

#define N_NODES 512
#define E_DIM   40
#define F_DIM   64
#define TOPK    10

typedef unsigned short u16;
typedef __attribute__((ext_vector_type(8))) short short8;   // 8 bf16 = 4 VGPRs
typedef __attribute__((ext_vector_type(4))) float f32x4;

__device__ __forceinline__ u16 f2bf(float f) {
    unsigned int b = __float_as_uint(f);
    b += 0x7fffu + ((b >> 16) & 1u);   // round-to-nearest-even
    return (u16)(b >> 16);
}
__device__ __forceinline__ float bf2f(u16 u) {
    return __uint_as_float(((unsigned int)u) << 16);
}

// ---------------------------------------------------------------------------
// Merged prologue: blocks 0..511 -> feats; blocks 512..575 -> fused weights.
// feats[n,e] = tanh(3*(emb1[n] @ lin1_w + b))   (idx is arange -> identity)
// Wt[d][k]   = bf16( k<64 ? (W_self@Wc_top)[k][d] : (W_neigh@Wc_bot)[k-64][d] )
// ap[0:64]   = W_self @ att[0:64];  ap[64:128] = W_neigh @ att[64:128]
__global__ void prep_kernel(const float* __restrict__ emb1,
                            const float* __restrict__ w,
                            const float* __restrict__ b,
                            float* __restrict__ feats,
                            const float* __restrict__ Ws, const float* __restrict__ Wn,
                            const float* __restrict__ Wc, const float* __restrict__ att,
                            u16* __restrict__ Wt, float* __restrict__ ap) {
    if (blockIdx.x < N_NODES) {
        int n = blockIdx.x, e = threadIdx.x;
        if (e >= E_DIM) return;
        const float* er = emb1 + n * E_DIM;
        float s = b[e];
        for (int k = 0; k < E_DIM; ++k) s += er[k] * w[k * E_DIM + e];
        feats[n * E_DIM + e] = tanhf(3.0f * s);
    } else {
        int f = blockIdx.x - N_NODES, d = threadIdx.x;   // 64 blocks x 64 threads
        float a = 0.f, bb = 0.f;
        for (int k = 0; k < 64; ++k) {
            a  += Ws[f * 64 + k] * Wc[k * 64 + d];
            bb += Wn[f * 64 + k] * Wc[(64 + k) * 64 + d];
        }
        Wt[d * 128 + f]      = f2bf(a);
        Wt[d * 128 + 64 + f] = f2bf(bb);
        float p0 = Ws[f * 64 + d] * att[d];
        float p1 = Wn[f * 64 + d] * att[64 + d];
        for (int off = 32; off > 0; off >>= 1) {
            p0 += __shfl_down(p0, off);
            p1 += __shfl_down(p1, off);
        }
        if (d == 0) { ap[f] = p0; ap[64 + f] = p1; }
    }
}

// ---------------------------------------------------------------------------
// Per row m: sim = feats[m] @ feats.T, iterative top-10 argmax, jax tie-break
// (equal values -> lower index). Output u16, rows padded to 16.
__global__ void topk_kernel(const float* __restrict__ feats, u16* __restrict__ top16) {
    int m = blockIdx.x, lane = threadIdx.x;  // 512 blocks x 64 threads (1 wave)
    __shared__ float sim[N_NODES];
    float fm[E_DIM];
#pragma unroll
    for (int k = 0; k < E_DIM; ++k) fm[k] = feats[m * E_DIM + k];
    for (int n = lane; n < N_NODES; n += 64) {
        const float* fr = feats + n * E_DIM;
        float s = 0.f;
#pragma unroll
        for (int k = 0; k < E_DIM; ++k) s += fm[k] * fr[k];
        sim[n] = s;
    }
    __syncthreads();
    for (int it = 0; it < TOPK; ++it) {
        float bv = -3.0e38f; int bi = 1 << 30;
        for (int n = lane; n < N_NODES; n += 64) {
            float v = sim[n];
            if (v > bv) { bv = v; bi = n; }       // ascending scan: min index on ties
        }
        for (int off = 32; off > 0; off >>= 1) {
            float ov = __shfl_down(bv, off);
            int   oi = __shfl_down(bi, off);
            if (ov > bv || (ov == bv && oi < bi)) { bv = ov; bi = oi; }
        }
        bi = __shfl(bi, 0);
        if (lane == 0) top16[m * 16 + it] = (u16)bi;
        __syncthreads();
        sim[bi] = -3.0e38f;
        __syncthreads();
    }
}

// ---------------------------------------------------------------------------
// Deterministic CSR: node n -> sorted list of hyperedges m with n in top[m].
__global__ void csr_kernel(const u16* __restrict__ top16, int* __restrict__ csr_off,
                           int* __restrict__ edges, float* __restrict__ inv_deg) {
    __shared__ int cnt[N_NODES];
    __shared__ int buf[N_NODES];
    __shared__ int pos[N_NODES];
    int t = threadIdx.x;                      // 512 threads
    cnt[t] = 0;
    __syncthreads();
    for (int j = 0; j < TOPK; ++j) atomicAdd(&cnt[(int)top16[t * 16 + j]], 1);
    __syncthreads();
    int my = cnt[t];
    buf[t] = my;
    __syncthreads();
    for (int s = 1; s < N_NODES; s <<= 1) {   // Hillis-Steele inclusive scan
        int v = (t >= s) ? buf[t - s] : 0;
        __syncthreads();
        buf[t] += v;
        __syncthreads();
    }
    int off = buf[t] - my;
    csr_off[t] = off;
    if (t == N_NODES - 1) csr_off[N_NODES] = buf[t];
    inv_deg[t] = 1.0f / (float)(my > 0 ? my : 1);
    pos[t] = off;
    __syncthreads();
    for (int j = 0; j < TOPK; ++j) {
        int n = (int)top16[t * 16 + j];
        int p = atomicAdd(&pos[n], 1);
        edges[p] = t;
    }
    __syncthreads();
    // canonicalize order (insertion sort, avg len 10) -> bitwise-deterministic sums
    for (int i = 1; i < my; ++i) {
        int key = edges[off + i], k = i - 1;
        while (k >= 0 && edges[off + k] > key) { edges[off + k + 1] = edges[off + k]; --k; }
        edges[off + k + 1] = key;
    }
}

// ---------------------------------------------------------------------------
// Main fused kernel: one 512-thread block per (b,l).
// LDS: cat[512][128] bf16 (cols 0-63 = x, 64-127 = xnr), XOR-swizzled 16B
// granules; he chunk [512][24] bf16 (16 used, rows padded to 48 B); scores.
#define CAT_OFF   0
#define HE_OFF    131072
#define SC_OFF    (131072 + 24576)
#define RED_OFF   (SC_OFF + 2048)
#define MISC_OFF  (RED_OFF + 2048)
#define SMEM_BYTES (MISC_OFF + 32)           // 159776 <= 163840

// byte offset of 16B granule g (8 bf16, f = g*8..g*8+7) of row n
__device__ __forceinline__ int cat_byte(int n, int g) {
    return n * 256 + ((g ^ (n & 15)) << 4);
}

__global__ __launch_bounds__(512, 2) void main_kernel(
    const float* __restrict__ x, const u16* __restrict__ top16,
    const int* __restrict__ csr_off, const int* __restrict__ edges,
    const float* __restrict__ inv_deg,
    const u16* __restrict__ Wt, const float* __restrict__ ap,
    float* __restrict__ out)
{
    extern __shared__ char smem[];
    float* sc  = (float*)(smem + SC_OFF);    // [512] scores, then exp values
    float* red = (float*)(smem + RED_OFF);   // [512]

    const int bl  = blockIdx.x;
    const int tid = threadIdx.x;
    const float* xr   = x   + (size_t)bl * N_NODES * F_DIM;
    float*       outr = out + (size_t)bl * N_NODES * F_DIM;

    // ---- stage: x slice -> cat cols 0..63 (bf16, swizzled) ----
    for (int i = 0; i < 8; ++i) {
        int gi = i * 512 + tid;             // 4096 x-granules
        int n = gi >> 3, g = gi & 7;
        const float4* s4 = (const float4*)(xr + n * 64 + g * 8);
        float4 a = s4[0], bq = s4[1];
        uint4 pk;
        pk.x = (unsigned)f2bf(a.x)  | ((unsigned)f2bf(a.y)  << 16);
        pk.y = (unsigned)f2bf(a.z)  | ((unsigned)f2bf(a.w)  << 16);
        pk.z = (unsigned)f2bf(bq.x) | ((unsigned)f2bf(bq.y) << 16);
        pk.w = (unsigned)f2bf(bq.z) | ((unsigned)f2bf(bq.w) << 16);
        *(uint4*)(smem + cat_byte(n, g)) = pk;
    }

    // hoist top indices for phase 1 (this thread's hyperedge m = tid)
    const u16* tp = top16 + tid * 16;
    uint4 tq = *(const uint4*)tp;
    unsigned tq2 = *(const unsigned*)(tp + 8);
    int tops[10] = { (int)(tq.x & 0xffff), (int)(tq.x >> 16),
                     (int)(tq.y & 0xffff), (int)(tq.y >> 16),
                     (int)(tq.z & 0xffff), (int)(tq.z >> 16),
                     (int)(tq.w & 0xffff), (int)(tq.w >> 16),
                     (int)(tq2 & 0xffff),  (int)(tq2 >> 16) };
    int o0 = csr_off[tid], o1 = csr_off[tid + 1];
    float inv = inv_deg[tid];
    __syncthreads();

    // ---- phases 1+2 over 4 f-chunks of 16 ----
    for (int c = 0; c < 4; ++c) {
        const int gb = c * 2;               // granules gb, gb+1 (f = c*16..c*16+15)
        // phase 1: he[m=tid, chunk] = leaky(0.1 * sum over top[m] of x rows)
        {
            float acc[16];
#pragma unroll
            for (int k = 0; k < 16; ++k) acc[k] = 0.f;
#pragma unroll
            for (int j = 0; j < TOPK; ++j) {
                int n = tops[j];
                short8 r0 = *(const short8*)(smem + cat_byte(n, gb));
                short8 r1 = *(const short8*)(smem + cat_byte(n, gb + 1));
#pragma unroll
                for (int k = 0; k < 8; ++k) {
                    acc[k]     += bf2f((u16)r0[k]);
                    acc[8 + k] += bf2f((u16)r1[k]);
                }
            }
            unsigned pk[8];
#pragma unroll
            for (int k = 0; k < 8; ++k) {
                float v0 = acc[2 * k] * 0.1f, v1 = acc[2 * k + 1] * 0.1f;
                v0 = v0 >= 0.f ? v0 : 0.2f * v0;
                v1 = v1 >= 0.f ? v1 : 0.2f * v1;
                pk[k] = (unsigned)f2bf(v0) | ((unsigned)f2bf(v1) << 16);
            }
            uint4* dst = (uint4*)(smem + HE_OFF + tid * 48);
            dst[0] = make_uint4(pk[0], pk[1], pk[2], pk[3]);
            dst[1] = make_uint4(pk[4], pk[5], pk[6], pk[7]);
        }
        __syncthreads();
        // phase 2: cat[n=tid, 64+chunk] = inv_deg * sum over edges(n) of he rows
        {
            float acc[16];
#pragma unroll
            for (int k = 0; k < 16; ++k) acc[k] = 0.f;
            for (int jj = o0; jj < o1; ++jj) {
                int e = edges[jj];
                short8 r0 = *(const short8*)(smem + HE_OFF + e * 48);
                short8 r1 = *(const short8*)(smem + HE_OFF + e * 48 + 16);
#pragma unroll
                for (int k = 0; k < 8; ++k) {
                    acc[k]     += bf2f((u16)r0[k]);
                    acc[8 + k] += bf2f((u16)r1[k]);
                }
            }
            uint4 w0, w1;
            w0.x = (unsigned)f2bf(acc[0] * inv)  | ((unsigned)f2bf(acc[1] * inv)  << 16);
            w0.y = (unsigned)f2bf(acc[2] * inv)  | ((unsigned)f2bf(acc[3] * inv)  << 16);
            w0.z = (unsigned)f2bf(acc[4] * inv)  | ((unsigned)f2bf(acc[5] * inv)  << 16);
            w0.w = (unsigned)f2bf(acc[6] * inv)  | ((unsigned)f2bf(acc[7] * inv)  << 16);
            w1.x = (unsigned)f2bf(acc[8] * inv)  | ((unsigned)f2bf(acc[9] * inv)  << 16);
            w1.y = (unsigned)f2bf(acc[10] * inv) | ((unsigned)f2bf(acc[11] * inv) << 16);
            w1.z = (unsigned)f2bf(acc[12] * inv) | ((unsigned)f2bf(acc[13] * inv) << 16);
            w1.w = (unsigned)f2bf(acc[14] * inv) | ((unsigned)f2bf(acc[15] * inv) << 16);
            *(uint4*)(smem + cat_byte(tid, 8 + gb))     = w0;
            *(uint4*)(smem + cat_byte(tid, 8 + gb + 1)) = w1;
        }
        __syncthreads();
    }

    // ---- phase 3: scores[n] = cat[n,:] . ap[0:128] ----
    {
        float s = 0.f;
#pragma unroll
        for (int g = 0; g < 16; ++g) {
            short8 r = *(const short8*)(smem + cat_byte(tid, g));
            float4 w0 = *(const float4*)(ap + g * 8);
            float4 w1 = *(const float4*)(ap + g * 8 + 4);
            s += bf2f((u16)r[0]) * w0.x + bf2f((u16)r[1]) * w0.y
               + bf2f((u16)r[2]) * w0.z + bf2f((u16)r[3]) * w0.w
               + bf2f((u16)r[4]) * w1.x + bf2f((u16)r[5]) * w1.y
               + bf2f((u16)r[6]) * w1.z + bf2f((u16)r[7]) * w1.w;
        }
        sc[tid] = s;
        red[tid] = s;
    }
    __syncthreads();

    // ---- softmax over 512 nodes ----
    for (int s = 256; s > 0; s >>= 1) {
        if (tid < s) red[tid] = fmaxf(red[tid], red[tid + s]);
        __syncthreads();
    }
    float M = red[0];
    __syncthreads();
    float ev = expf(sc[tid] - M);
    sc[tid] = ev;
    red[tid] = ev;
    __syncthreads();
    for (int s = 256; s > 0; s >>= 1) {
        if (tid < s) red[tid] += red[tid + s];
        __syncthreads();
    }
    if (tid == 0) *(float*)(smem + MISC_OFF) = 1.0f / red[0];
    __syncthreads();
    const float invS = *(const float*)(smem + MISC_OFF);

    // ---- phase 4: MFMA GEMM  out = diag(w) * (cat @ [A;B]) ----
    // wave w: rows w*64..w*64+63 (4 row-tiles) x 4 col-tiles, K=128 (4 steps)
    {
        const int wv = tid >> 6, lane = tid & 63;
        const int lrow = lane & 15, lk = lane >> 4;
        f32x4 acc[4][4];
#pragma unroll
        for (int rt = 0; rt < 4; ++rt)
#pragma unroll
            for (int ct = 0; ct < 4; ++ct) acc[rt][ct] = (f32x4)0.f;

#pragma unroll
        for (int ks = 0; ks < 4; ++ks) {
            short8 af[4], bfv[4];
#pragma unroll
            for (int rt = 0; rt < 4; ++rt) {
                int row = wv * 64 + rt * 16 + lrow;
                af[rt] = *(const short8*)(smem + cat_byte(row, ks * 4 + lk));
            }
#pragma unroll
            for (int ct = 0; ct < 4; ++ct) {
                int col = ct * 16 + lrow;
                bfv[ct] = *(const short8*)(Wt + col * 128 + ks * 32 + lk * 8);
            }
#pragma unroll
            for (int rt = 0; rt < 4; ++rt)
#pragma unroll
                for (int ct = 0; ct < 4; ++ct)
                    acc[rt][ct] = __builtin_amdgcn_mfma_f32_16x16x32_bf16(
                        af[rt], bfv[ct], acc[rt][ct], 0, 0, 0);
        }
        // epilogue: D row = (lane>>4)*4 + r, col = lane&15  [m89 layout]
#pragma unroll
        for (int rt = 0; rt < 4; ++rt) {
#pragma unroll
            for (int r = 0; r < 4; ++r) {
                int row = wv * 64 + rt * 16 + lk * 4 + r;
                float wgt = sc[row] * invS;
#pragma unroll
                for (int ct = 0; ct < 4; ++ct) {
                    int col = ct * 16 + lrow;
                    outr[row * 64 + col] = acc[rt][ct][r] * wgt;
                }
            }
        }
    }
}

// ---------------------------------------------------------------------------
extern "C" void kernel_launch(void* const* d_in, const int* in_sizes, int n_in,
                              void* d_out, int out_size, void* d_ws, size_t ws_size,
                              hipStream_t stream) {
    const float* x        = (const float*)d_in[0];
    // d_in[1] = idx (always arange -> identity, unused)
    const float* emb1     = (const float*)d_in[2];
    const float* lin1_w   = (const float*)d_in[3];
    const float* lin1_b   = (const float*)d_in[4];
    const float* W_self   = (const float*)d_in[5];
    const float* W_neigh  = (const float*)d_in[6];
    const float* W_concat = (const float*)d_in[7];
    const float* att      = (const float*)d_in[8];
    float* out = (float*)d_out;

    char* ws = (char*)d_ws;
    float* feats   = (float*)(ws + 0);        // 512*40*4  = 81920
    u16*   top16   = (u16*)  (ws + 81920);    // 512*16*2  = 16384
    int*   csr_off = (int*)  (ws + 98304);    // 513*4     = 2052
    int*   edges   = (int*)  (ws + 100416);   // 5120*4    = 20480
    float* inv_deg = (float*)(ws + 120896);   // 512*4
    u16*   Wt      = (u16*)  (ws + 122944);   // 64*128*2  = 16384
    float* ap      = (float*)(ws + 139328);   // 128*4

    prep_kernel<<<N_NODES + 64, 64, 0, stream>>>(emb1, lin1_w, lin1_b, feats,
                                                 W_self, W_neigh, W_concat, att, Wt, ap);
    topk_kernel<<<N_NODES, 64, 0, stream>>>(feats, top16);
    csr_kernel<<<1, N_NODES, 0, stream>>>(top16, csr_off, edges, inv_deg);

    (void)hipFuncSetAttribute((const void*)main_kernel,
                              hipFuncAttributeMaxDynamicSharedMemorySize, SMEM_BYTES);
    main_kernel<<<1024, 512, SMEM_BYTES, stream>>>(x, top16, csr_off, edges, inv_deg,
                                                   Wt, ap, out);
}